// Round 11
// baseline (147.292 us; speedup 1.0000x reference)
//
#include <hip/hip_runtime.h>
#include <hip/hip_fp16.h>
#include <math.h>

#define NPIX 262144   // 512*512
#define BATCH 4
#define RANK 8
#define CTXD 512
#define OUTF 210

// ---- workspace layout (float offsets) ----
#define XT_OFF   0      // xt[4][210] (840 floats)
#define ACC_OFF  1024   // 8 replicas x 176 accumulators (gram[4][36], S[4][8])
#define REP      8
#define NACC     176
#define WFS_OFF  4096   // byte 16384: __half wfs[32][NPIX] rank-major = 16 MiB

// ---------------- wave64 sum via DPP (result in lane 63) ---------------------
__device__ __forceinline__ float dpp_sum64(float x) {
  x += __int_as_float(__builtin_amdgcn_update_dpp(0, __float_as_int(x), 0x111, 0xf, 0xf, true)); // row_shr:1
  x += __int_as_float(__builtin_amdgcn_update_dpp(0, __float_as_int(x), 0x112, 0xf, 0xf, true)); // row_shr:2
  x += __int_as_float(__builtin_amdgcn_update_dpp(0, __float_as_int(x), 0x114, 0xf, 0xf, true)); // row_shr:4
  x += __int_as_float(__builtin_amdgcn_update_dpp(0, __float_as_int(x), 0x118, 0xf, 0xf, true)); // row_shr:8
  x += __int_as_float(__builtin_amdgcn_update_dpp(0, __float_as_int(x), 0x142, 0xf, 0xf, true)); // row_bcast:15
  x += __int_as_float(__builtin_amdgcn_update_dpp(0, __float_as_int(x), 0x143, 0xf, 0xf, true)); // row_bcast:31
  return x;
}

// ---------------- threefry2x32 (JAX original scheme, key=(0,42)) -------------
__device__ __forceinline__ void threefry2x32_pair(unsigned int x0, unsigned int x1,
                                                  unsigned int* o0, unsigned int* o1) {
  const unsigned int ks0 = 0u, ks1 = 42u, ks2 = 0x1BD11BF0u;
  x0 += ks0; x1 += ks1;
#define TF_R(rot) { x0 += x1; x1 = (x1 << rot) | (x1 >> (32 - rot)); x1 ^= x0; }
  TF_R(13) TF_R(15) TF_R(26) TF_R(6)
  x0 += ks1; x1 += ks2 + 1u;
  TF_R(17) TF_R(29) TF_R(16) TF_R(24)
  x0 += ks2; x1 += ks0 + 2u;
  TF_R(13) TF_R(15) TF_R(26) TF_R(6)
  x0 += ks0; x1 += ks1 + 3u;
  TF_R(17) TF_R(29) TF_R(16) TF_R(24)
  x0 += ks1; x1 += ks2 + 4u;
  TF_R(13) TF_R(15) TF_R(26) TF_R(6)
  x0 += ks2; x1 += ks0 + 5u;
#undef TF_R
  *o0 = x0; *o1 = x1;
}

// bits -> uniform(-1,1) -> sqrt(2)*erfinv. Giles polys TRUNCATED 9->5 terms:
// abs error <= 2.2e-3 (w<5) / 7.5e-3 (w>=5) in the normal sample; noise is
// scaled by ~4e-6, so worst-case output perturbation ~1e-8 << 1.05e-5 budget.
__device__ __forceinline__ float fast_normal(unsigned int bits) {
  unsigned int fb = (bits >> 9) | 0x3f800000u;
  float f = __uint_as_float(fb) - 1.0f;                 // [0,1)
  const float lo = -0.99999994039535522461f;            // nextafter(-1,0) f32
  float u = f * 2.0f + lo;
  u = fmaxf(u, lo);
  float w = -__logf(fmaf(-u, u, 1.0f));                 // -log(1-u^2)
  float q1 = w - 2.5f;
  float p1 = 0.00021858087f;
  p1 = fmaf(p1, q1, -0.00125372503f);
  p1 = fmaf(p1, q1, -0.00417768164f);
  p1 = fmaf(p1, q1, 0.246640727f);
  p1 = fmaf(p1, q1, 1.50140941f);
  float q2 = sqrtf(w) - 3.0f;
  float p2 = 0.00573950773f;
  p2 = fmaf(p2, q2, -0.0076224613f);
  p2 = fmaf(p2, q2, 0.00943887047f);
  p2 = fmaf(p2, q2, 1.00167406f);
  p2 = fmaf(p2, q2, 2.83297682f);
  float pr = (w < 5.0f) ? p1 : p2;
  return 1.4142135623730951f * pr * u;
}

// ---------------- K1: ctx MLP + accumulator zeroing --------------------------
__global__ __launch_bounds__(256) void k_ctx(const float* __restrict__ x,
                                             const float* __restrict__ cw,
                                             const float* __restrict__ cb,
                                             float* __restrict__ ws) {
  // zero the REP*NACC atomic accumulators (replaces a separate memset dispatch;
  // kernel boundary orders this before k_wfs's atomics)
  int gi = blockIdx.x * 256 + threadIdx.x;
  if (gi < REP * NACC) ws[ACC_OFF + gi] = 0.f;

  int lane = threadIdx.x & 63, wv = threadIdx.x >> 6;
  int row = blockIdx.x * 4 + wv;            // 0..839 (grid=210 exactly covers)
  int b = row / OUTF, i = row - b * OUTF;
  const float* wrow = cw + i * CTXD;
  const float* xr = x + b * CTXD;
  float acc = 0.f;
#pragma unroll
  for (int u = 0; u < CTXD; u += 64)
    acc = fmaf(wrow[u + lane], xr[u + lane], acc);
  acc = dpp_sum64(acc);
  if (lane == 63) ws[XT_OFF + row] = acc + cb[i];
}

// ---------------- K2: wf compute + fp16 store, Gram + per-rank sums ----------
// Batch-split: each block handles 2 of 4 batches (gram is block-diagonal in b),
// doubling the grid to 2048 blocks -> 16 waves/CU (was 8: latency trap).
// blockIdx&1 = batch pair, so the two blocks sharing a pixel range dispatch
// back-to-back and the second weight read hits L2/L3.
// 2 px/thread, float4 weight loads, half2 stores streamed in-loop (no packing
// union — R6 spill trap). _stable clamp dropped (fp16 flushes 1e-12 anyway).
__global__ __launch_bounds__(128) void k_wfs(const float* __restrict__ wts,
                                             float* __restrict__ ws) {
  __shared__ float4 mods[16][3];   // [bb*8+k][0]=A0,B0  [1]=A1,B1  [2]=biases
  __shared__ float gred[2][88];    // [0:72) gram (bb*36+i), [72:88) S (bb*8+k)
  const float* xt = ws + XT_OFF;
  __half2* wfs2 = (__half2*)((char*)ws + WFS_OFF * 4);
  int t = threadIdx.x;
  int bp = blockIdx.x & 1;                  // batch pair: batches {2bp, 2bp+1}

  if (t < 48) {
    int bk = t / 3, part = t - bk * 3;      // bk: 0..15 local
    int bb = bk >> 3, k = bk & 7;
    const float* xb = xt + (bp * 2 + bb) * OUTF + 12 * k;
#define GATE(j) (xb[j] * tanhf(xb[105 + (j)]))
    float4 r;
    if (part < 2) {
      float c0 = GATE(2 * part) + 0.5f;
      float c1 = GATE(2 * part + 1);
      float s0 = GATE(8 + 2 * part) + 1.0f;
      float s1 = GATE(9 + 2 * part);
      float omc = 1.0f - c0;
      r.x = s0 * omc + s1 * c1;   // A_r
      r.y = s1 * omc - s0 * c1;   // A_i
      r.z = s0 * c0 - s1 * c1;    // B_r
      r.w = s1 * c0 + s0 * c1;    // B_i
    } else {
      r.x = GATE(4); r.y = GATE(5); r.z = GATE(6); r.w = GATE(7);
    }
#undef GATE
    mods[bk][part] = r;
  }
  __syncthreads();

  int tp = (blockIdx.x >> 1) * 128 + t;     // 0..131071, 2 adjacent pixels each
  const float4* w4 = (const float4*)wts;    // float4 = 2 complex px; 2^17 per page
  float wf[2][RANK][2];                     // [bb][k][px]
#pragma unroll
  for (int k = 0; k < RANK; ++k) {
    // ld[lerp][comp] = {px0.re, px0.im, px1.re, px1.im}
    float4 ld[2][2];
#pragma unroll
    for (int s = 0; s < 2; ++s)
#pragma unroll
      for (int comp = 0; comp < 2; ++comp)
        ld[s][comp] = w4[((k * 4 + s * 2 + comp) << 17) + tp];
#pragma unroll
    for (int bb = 0; bb < 2; ++bb) {
      float4 P  = mods[bb * 8 + k][0];
      float4 Q  = mods[bb * 8 + k][1];
      float4 Bb = mods[bb * 8 + k][2];
      __half2 st;
#pragma unroll
      for (int j = 0; j < 2; ++j) {
        float w0r = j ? ld[0][0].z : ld[0][0].x;
        float w0i = j ? ld[0][0].w : ld[0][0].y;
        float w1r = j ? ld[1][0].z : ld[1][0].x;
        float w1i = j ? ld[1][0].w : ld[1][0].y;
        float v0r = j ? ld[0][1].z : ld[0][1].x;
        float v0i = j ? ld[0][1].w : ld[0][1].y;
        float v1r = j ? ld[1][1].z : ld[1][1].x;
        float v1i = j ? ld[1][1].w : ld[1][1].y;
        float zr0 = fmaf(P.x, w0r, fmaf(-P.y, w0i, fmaf(P.z, w1r, fmaf(-P.w, w1i, Bb.x))));
        float zi0 = fmaf(P.y, w0r, fmaf( P.x, w0i, fmaf(P.w, w1r, fmaf( P.z, w1i, Bb.y))));
        float zr1 = fmaf(Q.x, v0r, fmaf(-Q.y, v0i, fmaf(Q.z, v1r, fmaf(-Q.w, v1i, Bb.z))));
        float zi1 = fmaf(Q.y, v0r, fmaf( Q.x, v0i, fmaf(Q.w, v1r, fmaf( Q.z, v1i, Bb.w))));
        float d2 = fmaxf(fmaf(zr1, zr1, zi1 * zi1), 1e-12f);
        float rn = __builtin_amdgcn_rsqf(d2);          // v_rsq_f32, ~1 ulp
        float w = fmaf(zr0, zr1, zi0 * zi1) * rn;
        wf[bb][k][j] = w;
        if (j) st.y = __float2half(w); else st.x = __float2half(w);
      }
      wfs2[(((bp * 2 + bb) * RANK + k) << 17) + tp] = st;  // one 4B store, coalesced
    }
  }
  // reduce gram[2][36] (upper-tri incl diag) + S[2][8]; 2-px register pre-sum
  int lane = t & 63, wv = t >> 6;
#pragma unroll
  for (int bb = 0; bb < 2; ++bb) {
    int idx = bb * 36;
#pragma unroll
    for (int r = 0; r < RANK; ++r)
#pragma unroll
      for (int s = r; s < RANK; ++s, ++idx) {
        float pr = dpp_sum64(fmaf(wf[bb][r][0], wf[bb][s][0], wf[bb][r][1] * wf[bb][s][1]));
        if (lane == 63) gred[wv][idx] = pr;
      }
  }
#pragma unroll
  for (int bb = 0; bb < 2; ++bb)
#pragma unroll
    for (int k = 0; k < RANK; ++k) {
      float pr = dpp_sum64(wf[bb][k][0] + wf[bb][k][1]);
      if (lane == 63) gred[wv][72 + bb * 8 + k] = pr;
    }
  __syncthreads();
  if (t < 88) {
    float s = gred[0][t] + gred[1][t];
    int g;
    if (t < 72) { int bb = t / 36, i = t - bb * 36; g = (bp * 2 + bb) * 36 + i; }
    else        { int u = t - 72;  int bb = u >> 3; g = 144 + (bp * 2 + bb) * 8 + (u & 7); }
    // 8-way replicated accumulators: same-address contention /8
    atomicAdd(ws + ACC_OFF + (blockIdx.x & (REP - 1)) * NACC + g, s);
  }
}

// ---------------- K3: analytic stats + output + noise ------------------------
__global__ __launch_bounds__(256) void k_out(const float* __restrict__ ws,
                                             float* __restrict__ out) {
  const float* xt = ws + XT_OFF;
  const __half* wfs16 = (const __half*)((const char*)ws + WFS_OFF * 4);
  __shared__ float G[NACC];                  // [0:144) gram, [144:176) S
  __shared__ float n1[32], Ml[256], vv[32], scl[32], ca[4], wrl[BATCH][9];
  __shared__ float in2[32], mnv[32], sdv[32];
  int t = threadIdx.x;
  if (t < NACC) {
    float s = 0.f;
#pragma unroll
    for (int rep = 0; rep < REP; ++rep) s += ws[ACC_OFF + rep * NACC + t];
    G[t] = s;
  }
  if (t >= 192 && t < 192 + BATCH) {         // wr softmax (per-batch thread)
    int b = t - 192;
    float raw[9];
#pragma unroll
    for (int j = 0; j < 9; ++j)
      raw[j] = xt[b * OUTF + 96 + j] * tanhf(xt[b * OUTF + 201 + j]);
    raw[8] += 0.35355339059327373f;          // 1/sqrt(8)
    double ss = 0.0;
    for (int j = 0; j < 9; ++j) ss += (double)raw[j] * (double)raw[j];
    float n = fmaxf((float)sqrt(ss), 1e-12f);
    float y[9]; float m = -1e30f;
    for (int j = 0; j < 9; ++j) { y[j] = raw[j] / n; m = fmaxf(m, y[j]); }
    float e[9]; double se = 0.0;
    for (int j = 0; j < 9; ++j) { e[j] = expf(y[j] - m); se += (double)e[j]; }
    for (int j = 0; j < 9; ++j) wrl[b][j] = e[j] / (float)se;
  }
  __syncthreads();
  if (t < 32) {
    int b = t >> 3, k = t & 7;
    int di = k * 8 - (k * (k - 1)) / 2;
    n1[t] = fmaxf(sqrtf(G[b * 36 + di]), 1e-12f);
  }
  __syncthreads();
  {
    int b = t >> 6, k = (t >> 3) & 7, s = t & 7;
    float m;
    if (k == s) {
      m = 1.0f / n1[b * 8 + k];
    } else {
      int r0 = k < s ? k : s, s0 = k < s ? s : k;
      int gi = r0 * 8 - (r0 * (r0 - 1)) / 2 + (s0 - r0);
      float simv = G[b * 36 + gi] / (n1[b * 8 + k] * n1[b * 8 + s]);
      m = -0.0050507627227610544f * simv / n1[b * 8 + s];  // (0.1/sqrt(8))/7
    }
    Ml[t] = m;
  }
  __syncthreads();
  if (t < 32) {
    int b = t >> 3, k = t & 7;
    // sum = M.S ; sumsq = (M G M^T)_kk — exact linear algebra of the 2nd pass
    float sum = 0.f, sq = 0.f;
#pragma unroll
    for (int s = 0; s < 8; ++s) {
      float ms = Ml[b * 64 + k * 8 + s];
      sum = fmaf(ms, G[144 + b * 8 + s], sum);
#pragma unroll
      for (int u = 0; u < 8; ++u) {
        int r0 = s < u ? s : u, s0 = s < u ? u : s;
        int gi = r0 * 8 - (r0 * (r0 - 1)) / 2 + (s0 - r0);
        sq = fmaf(ms * Ml[b * 64 + k * 8 + u], G[b * 36 + gi], sq);
      }
    }
    float n2 = fmaxf(sqrtf(fmaxf(sq, 0.f)), 1e-12f);
    float mean = sum / n2 * (1.0f / NPIX);
    float sy2 = sq / (n2 * n2);
    float var = (sy2 - (float)NPIX * mean * mean) * (1.0f / (float)(NPIX - 1));
    var = fmaxf(var, 0.f);
    float sd = fmaxf(sqrtf(var), 1e-12f);
    in2[t] = 1.f / n2; mnv[t] = mean; sdv[t] = sd;
  }
  __syncthreads();
  if (t < 32) {
    int b = t >> 3, s = t & 7;
    float acc = 0.f;
#pragma unroll
    for (int k = 0; k < 8; ++k)
      acc += wrl[b][k] * Ml[b * 64 + k * 8 + s] * in2[b * 8 + k];
    vv[t] = acc;
    scl[t] = wrl[b][s] * 0.01f * sdv[t];
  }
  if (t < BATCH) {
    float a = 0.f;
#pragma unroll
    for (int k = 0; k < 8; ++k) a += wrl[t][k] * 0.01f * mnv[t * 8 + k];
    ca[t] = a;
  }
  __syncthreads();

  int p = blockIdx.x * 256 + t;
  float o[4];
#pragma unroll
  for (int b = 0; b < 4; ++b) {
    float acc = ca[b];
#pragma unroll
    for (int s = 0; s < 8; ++s)
      acc = fmaf(vv[b * 8 + s], __half2float(wfs16[((b * RANK + s) << 18) + p]), acc);
    o[b] = acc;
  }
  // noise: flat j=(b*8+k)*NPIX+p over 2^23 elems; (j, j+2^22) share a threefry block
#pragma unroll
  for (int bk = 0; bk < 16; ++bk) {
    unsigned int i = ((unsigned int)bk << 18) + (unsigned int)p;
    unsigned int r0, r1;
    threefry2x32_pair(i, i + 0x400000u, &r0, &r1);
    int b2 = bk >> 3, k = bk & 7;
    o[b2]     += scl[b2 * 8 + k]       * fast_normal(r0);
    o[b2 + 2] += scl[(b2 + 2) * 8 + k] * fast_normal(r1);
  }
#pragma unroll
  for (int b = 0; b < 4; ++b) out[(b << 18) + p] = o[b];
}

extern "C" void kernel_launch(void* const* d_in, const int* in_sizes, int n_in,
                              void* d_out, int out_size, void* d_ws, size_t ws_size,
                              hipStream_t stream) {
  const float* x   = (const float*)d_in[0];
  const float* cw  = (const float*)d_in[1];
  const float* cb  = (const float*)d_in[2];
  const float* wts = (const float*)d_in[3];
  float* out = (float*)d_out;
  float* ws  = (float*)d_ws;

  k_ctx <<<210,  256, 0, stream>>>(x, cw, cb, ws);   // also zeroes accumulators
  k_wfs <<<2048, 128, 0, stream>>>(wts, ws);
  k_out <<<1024, 256, 0, stream>>>(ws, out);
}